// Round 1
// baseline (966.346 us; speedup 1.0000x reference)
//
#include <hip/hip_runtime.h>
#include <cstdint>
#include <cstddef>

#define H_ 2880
#define E_ 8
#define FF_ 2880
#define TWO_FF 5760
#define S_ 2048
#define CLIPV 7.0f
#define AUXC 0.01f

typedef __attribute__((ext_vector_type(8))) short bf16x8;
typedef __attribute__((ext_vector_type(4))) float f32x4;

// ---------------- workspace layout (bytes) ----------------
#define WS_COUNTS   0         // int[8]
#define WS_FILL     32        // int[8]
#define WS_BASE     64        // int[9]
#define WS_SCHED_E  128       // int[48]
#define WS_SCHED_R  320       // int[48]
#define WS_IDX2     1024      // int[2*S]
#define WS_W2       17408     // float[2*S]
#define WS_PROBS    33792     // float[8*S]
#define WS_ENT      99328     // float[S]
#define WS_TOKL     107520    // int[4096]
#define WS_ASSW     123904    // float[4096]
#define WS_ACT      140544    // ushort[4096*2880] bf16

__device__ __forceinline__ unsigned int f2bf(float f) {
  union { float f; unsigned int u; } c; c.f = f;
  return (c.u + 0x7FFFu + ((c.u >> 16) & 1u)) >> 16;   // RNE truncate to bf16
}

// ---------------- router: logits, top2, probs, entropy ----------------
__global__ void k_router(const float* __restrict__ x, const float* __restrict__ rw,
                         const float* __restrict__ rb, int* __restrict__ counts,
                         int* __restrict__ idx2, float* __restrict__ wtop,
                         float* __restrict__ probs, float* __restrict__ ent) {
  int wave = threadIdx.x >> 6, lane = threadIdx.x & 63;
  int s = blockIdx.x * 4 + wave;
  if (s >= S_) return;
  const float* xr = x + (size_t)s * H_;
  float acc[E_];
#pragma unroll
  for (int e = 0; e < E_; ++e) acc[e] = 0.f;
  for (int k = lane; k < H_; k += 64) {
    float xv = xr[k];
#pragma unroll
    for (int e = 0; e < E_; ++e) acc[e] = fmaf(xv, rw[e * H_ + k], acc[e]);
  }
#pragma unroll
  for (int e = 0; e < E_; ++e) {
#pragma unroll
    for (int off = 32; off > 0; off >>= 1) acc[e] += __shfl_xor(acc[e], off, 64);
    acc[e] += rb[e];
  }
  if (lane == 0) {
    int i1 = 0; float v1 = acc[0];
#pragma unroll
    for (int e = 1; e < E_; ++e) if (acc[e] > v1) { v1 = acc[e]; i1 = e; }
    int i2 = -1; float v2 = -3.4e38f;
#pragma unroll
    for (int e = 0; e < E_; ++e) if (e != i1 && acc[e] > v2) { v2 = acc[e]; i2 = e; }
    float w1 = 1.f / (1.f + expf(v2 - v1));
    float w2v = 1.f - w1;
    float m = v1;
    float se = 0.f; float p[E_];
#pragma unroll
    for (int e = 0; e < E_; ++e) { p[e] = expf(acc[e] - m); se += p[e]; }
    float inv = 1.f / se; float ents = 0.f;
#pragma unroll
    for (int e = 0; e < E_; ++e) {
      p[e] *= inv;
      ents -= p[e] * logf(p[e] + 1e-10f);
      probs[(size_t)s * E_ + e] = p[e];
    }
    ent[s] = ents;
    idx2[2 * s] = i1; idx2[2 * s + 1] = i2;
    wtop[2 * s] = w1; wtop[2 * s + 1] = w2v;
    atomicAdd(&counts[i1], 1); atomicAdd(&counts[i2], 1);
  }
}

// ---------------- finalize: scalars + schedule (deterministic fixed-order) ----------------
__global__ void k_finalize(const int* __restrict__ counts, const float* __restrict__ probs,
                           const float* __restrict__ ent, const int* __restrict__ idx2,
                           const float* __restrict__ wtop, float* __restrict__ outsc,
                           int* __restrict__ base, int* __restrict__ sched_e,
                           int* __restrict__ sched_r) {
  __shared__ float red[256];
  __shared__ float tot[17];
  int t = threadIdx.x;
  float imp[8], ld[8]; float es = 0.f;
#pragma unroll
  for (int e = 0; e < 8; ++e) { imp[e] = 0.f; ld[e] = 0.f; }
  for (int s = t; s < S_; s += 256) {
#pragma unroll
    for (int e = 0; e < 8; ++e) imp[e] += probs[(size_t)s * 8 + e];
    es += ent[s];
    int e0 = idx2[2 * s], e1 = idx2[2 * s + 1];
    float a = wtop[2 * s], b = wtop[2 * s + 1];
#pragma unroll
    for (int e = 0; e < 8; ++e)
      ld[e] += (e0 == e ? a : 0.f) + (e1 == e ? b : 0.f);
  }
#pragma unroll
  for (int q = 0; q < 17; ++q) {
    float v = (q < 8) ? imp[q] : ((q < 16) ? ld[q - 8] : es);
    red[t] = v; __syncthreads();
    for (int o = 128; o > 0; o >>= 1) { if (t < o) red[t] += red[t + o]; __syncthreads(); }
    if (t == 0) tot[q] = red[0];
    __syncthreads();
  }
  if (t == 0) {
    float aux = 0.f;
#pragma unroll
    for (int e = 0; e < 8; ++e) aux += (tot[e] / (float)S_) * (tot[8 + e] / (float)S_);
    aux *= AUXC * (float)E_;
    outsc[0] = aux;
#pragma unroll
    for (int e = 0; e < 8; ++e) outsc[1 + e] = tot[8 + e] / (float)S_;
    outsc[9] = tot[16] / (float)S_;
    int b0 = 0; base[0] = 0; int ns = 0;
    for (int e = 0; e < 8; ++e) {
      int c = counts[e];
      for (int r = 0; r < c; r += 128) { sched_e[ns] = e; sched_r[ns] = r; ++ns; }
      b0 += c; base[e + 1] = b0;
    }
    for (; ns < 48; ++ns) sched_e[ns] = -1;
  }
}

// ---------------- fill per-expert token lists ----------------
__global__ void k_fill(const int* __restrict__ idx2, const float* __restrict__ wtop,
                       const int* __restrict__ base, int* __restrict__ fill,
                       int* __restrict__ tokl, float* __restrict__ assw) {
  int s = blockIdx.x * 256 + threadIdx.x;
  if (s >= S_) return;
#pragma unroll
  for (int k = 0; k < 2; ++k) {
    int e = idx2[2 * s + k];
    int p = base[e] + atomicAdd(&fill[e], 1);
    tokl[p] = s;
    assw[p] = wtop[2 * s + k];
  }
}

// ---------------- GEMM1: x -> act (up/gate fused, bias+clip+silu) ----------------
__global__ __launch_bounds__(256, 2) void k_gemm1(
    const float* __restrict__ x, const float* __restrict__ Win, const float* __restrict__ bin,
    const int* __restrict__ sched_e, const int* __restrict__ sched_r,
    const int* __restrict__ base, const int* __restrict__ counts,
    const int* __restrict__ tokl, unsigned short* __restrict__ act) {
  int slot = blockIdx.y;
  int e = sched_e[slot];
  if (e < 0) return;
  int row0 = sched_r[slot];
  int n_e = counts[e];
  int rbase = base[e];
  int n0 = blockIdx.x * 96;
  const float* We = Win + (size_t)e * H_ * TWO_FF;
  int tid = threadIdx.x;
  int lane = tid & 63, wv = tid >> 6;
  int wm = wv >> 1, wn = wv & 1;

  __shared__ __align__(16) unsigned short Al[4][128][8];
  __shared__ __align__(16) unsigned short Bu[4][96][8];
  __shared__ __align__(16) unsigned short Bg[4][96][8];
  __shared__ int toks[128];

  if (tid < 128) {
    int r = row0 + tid;
    if (r >= n_e) r = n_e - 1;
    toks[tid] = tokl[rbase + r];
  }
  __syncthreads();

  int a_row[4], a_kq[4];
  const float* a_ptr[4];
#pragma unroll
  for (int i = 0; i < 4; ++i) {
    int cell = tid + 256 * i;
    a_kq[i] = cell >> 7;
    a_row[i] = cell & 127;
    a_ptr[i] = x + (size_t)toks[a_row[i]] * H_ + a_kq[i] * 4;
  }
  int b_j[6], b_kq[6], b_tile[6];
  const float* b_ptr[6];
#pragma unroll
  for (int i = 0; i < 6; ++i) {
    int cell = tid + 256 * i;
    int tile = (cell >= 768) ? 1 : 0;
    int c = cell - tile * 768;
    int kq = c / 96;
    int j = c - kq * 96;
    b_tile[i] = tile; b_kq[i] = kq; b_j[i] = j;
    b_ptr[i] = We + (size_t)(kq * 4) * TWO_FF + n0 + j + (tile ? FF_ : 0);
  }

  f32x4 aU[4][3], aG[4][3];
#pragma unroll
  for (int m = 0; m < 4; ++m)
#pragma unroll
    for (int n = 0; n < 3; ++n) { aU[m][n] = (f32x4)0.f; aG[m][n] = (f32x4)0.f; }

  float4 sA[4];
  float sB[6][4];
#pragma unroll
  for (int i = 0; i < 4; ++i) sA[i] = *(const float4*)(a_ptr[i]);
#pragma unroll
  for (int i = 0; i < 6; ++i) {
    const float* p = b_ptr[i];
    sB[i][0] = p[0]; sB[i][1] = p[TWO_FF]; sB[i][2] = p[2 * TWO_FF]; sB[i][3] = p[3 * TWO_FF];
  }

  const int NK = H_ / 32;  // 90
  for (int kt = 0; kt < NK; ++kt) {
    __syncthreads();
#pragma unroll
    for (int i = 0; i < 4; ++i) {
      uint2 v;
      v.x = f2bf(sA[i].x) | (f2bf(sA[i].y) << 16);
      v.y = f2bf(sA[i].z) | (f2bf(sA[i].w) << 16);
      *(uint2*)&Al[a_kq[i] >> 1][a_row[i]][(a_kq[i] & 1) * 4] = v;
    }
#pragma unroll
    for (int i = 0; i < 6; ++i) {
      uint2 v;
      v.x = f2bf(sB[i][0]) | (f2bf(sB[i][1]) << 16);
      v.y = f2bf(sB[i][2]) | (f2bf(sB[i][3]) << 16);
      unsigned short (*Bt)[96][8] = b_tile[i] ? Bg : Bu;
      *(uint2*)&Bt[b_kq[i] >> 1][b_j[i]][(b_kq[i] & 1) * 4] = v;
    }
    if (kt + 1 < NK) {
      size_t off = (size_t)(kt + 1) * 32;
#pragma unroll
      for (int i = 0; i < 4; ++i) sA[i] = *(const float4*)(a_ptr[i] + off);
#pragma unroll
      for (int i = 0; i < 6; ++i) {
        const float* p = b_ptr[i] + off * TWO_FF;
        sB[i][0] = p[0]; sB[i][1] = p[TWO_FF]; sB[i][2] = p[2 * TWO_FF]; sB[i][3] = p[3 * TWO_FF];
      }
    }
    __syncthreads();
    bf16x8 af[4];
#pragma unroll
    for (int m = 0; m < 4; ++m)
      af[m] = *(const bf16x8*)&Al[lane >> 4][wm * 64 + m * 16 + (lane & 15)][0];
#pragma unroll
    for (int n = 0; n < 3; ++n) {
      bf16x8 bu = *(const bf16x8*)&Bu[lane >> 4][wn * 48 + n * 16 + (lane & 15)][0];
      bf16x8 bg = *(const bf16x8*)&Bg[lane >> 4][wn * 48 + n * 16 + (lane & 15)][0];
#pragma unroll
      for (int m = 0; m < 4; ++m) {
        aU[m][n] = __builtin_amdgcn_mfma_f32_16x16x32_bf16(af[m], bu, aU[m][n], 0, 0, 0);
        aG[m][n] = __builtin_amdgcn_mfma_f32_16x16x32_bf16(af[m], bg, aG[m][n], 0, 0, 0);
      }
    }
  }

#pragma unroll
  for (int n = 0; n < 3; ++n) {
    int col = n0 + wn * 48 + n * 16 + (lane & 15);
    float bu_b = bin[(size_t)e * TWO_FF + col];
    float bg_b = bin[(size_t)e * TWO_FF + FF_ + col];
#pragma unroll
    for (int m = 0; m < 4; ++m) {
#pragma unroll
      for (int q = 0; q < 4; ++q) {
        int r = wm * 64 + m * 16 + (lane >> 4) * 4 + q;
        if (row0 + r < n_e) {
          float u = aU[m][n][q] + bu_b;
          float g = aG[m][n][q] + bg_b;
          u = fminf(fmaxf(u, -CLIPV), CLIPV);
          g = fminf(fmaxf(g, -CLIPV), CLIPV);
          float sig = 1.f / (1.f + expf(-g));
          float a = g * sig * u;
          act[(size_t)(rbase + row0 + r) * FF_ + col] = (unsigned short)f2bf(a);
        }
      }
    }
  }
}

// ---------------- GEMM2: act -> out (scatter-add weighted) ----------------
__global__ __launch_bounds__(256, 2) void k_gemm2(
    const unsigned short* __restrict__ act, const float* __restrict__ Wout,
    const float* __restrict__ bout, const int* __restrict__ sched_e,
    const int* __restrict__ sched_r, const int* __restrict__ base,
    const int* __restrict__ counts, const int* __restrict__ tokl,
    const float* __restrict__ assw, float* __restrict__ out) {
  int slot = blockIdx.y;
  int e = sched_e[slot];
  if (e < 0) return;
  int row0 = sched_r[slot];
  int n_e = counts[e];
  int rbase = base[e];
  int n0 = blockIdx.x * 96;
  const float* We = Wout + (size_t)e * FF_ * H_;
  int tid = threadIdx.x;
  int lane = tid & 63, wv = tid >> 6;
  int wm = wv >> 1, wn = wv & 1;

  __shared__ __align__(16) unsigned short Al[4][128][8];
  __shared__ __align__(16) unsigned short Bl[4][96][8];

  int a_row[4], a_kq[4];
  const unsigned short* a_ptr[4];
#pragma unroll
  for (int i = 0; i < 4; ++i) {
    int cell = tid + 256 * i;
    a_kq[i] = cell >> 7;
    a_row[i] = cell & 127;
    int r = row0 + a_row[i];
    if (r >= n_e) r = n_e - 1;
    a_ptr[i] = act + (size_t)(rbase + r) * FF_ + a_kq[i] * 4;
  }
  int b_j[3], b_kq[3];
  const float* b_ptr[3];
#pragma unroll
  for (int i = 0; i < 3; ++i) {
    int cell = tid + 256 * i;
    int kq = cell / 96;
    int j = cell - kq * 96;
    b_kq[i] = kq; b_j[i] = j;
    b_ptr[i] = We + (size_t)(kq * 4) * H_ + n0 + j;
  }

  f32x4 acc[4][3];
#pragma unroll
  for (int m = 0; m < 4; ++m)
#pragma unroll
    for (int n = 0; n < 3; ++n) acc[m][n] = (f32x4)0.f;

  uint2 sA[4];
  float sB[3][4];
#pragma unroll
  for (int i = 0; i < 4; ++i) sA[i] = *(const uint2*)(a_ptr[i]);
#pragma unroll
  for (int i = 0; i < 3; ++i) {
    const float* p = b_ptr[i];
    sB[i][0] = p[0]; sB[i][1] = p[H_]; sB[i][2] = p[2 * H_]; sB[i][3] = p[3 * H_];
  }

  const int NK = FF_ / 32;  // 90
  for (int kt = 0; kt < NK; ++kt) {
    __syncthreads();
#pragma unroll
    for (int i = 0; i < 4; ++i)
      *(uint2*)&Al[a_kq[i] >> 1][a_row[i]][(a_kq[i] & 1) * 4] = sA[i];
#pragma unroll
    for (int i = 0; i < 3; ++i) {
      uint2 v;
      v.x = f2bf(sB[i][0]) | (f2bf(sB[i][1]) << 16);
      v.y = f2bf(sB[i][2]) | (f2bf(sB[i][3]) << 16);
      *(uint2*)&Bl[b_kq[i] >> 1][b_j[i]][(b_kq[i] & 1) * 4] = v;
    }
    if (kt + 1 < NK) {
      size_t off = (size_t)(kt + 1) * 32;
#pragma unroll
      for (int i = 0; i < 4; ++i) sA[i] = *(const uint2*)(a_ptr[i] + off);
#pragma unroll
      for (int i = 0; i < 3; ++i) {
        const float* p = b_ptr[i] + off * H_;
        sB[i][0] = p[0]; sB[i][1] = p[H_]; sB[i][2] = p[2 * H_]; sB[i][3] = p[3 * H_];
      }
    }
    __syncthreads();
    bf16x8 af[4];
#pragma unroll
    for (int m = 0; m < 4; ++m)
      af[m] = *(const bf16x8*)&Al[lane >> 4][wm * 64 + m * 16 + (lane & 15)][0];
#pragma unroll
    for (int n = 0; n < 3; ++n) {
      bf16x8 bf = *(const bf16x8*)&Bl[lane >> 4][wn * 48 + n * 16 + (lane & 15)][0];
#pragma unroll
      for (int m = 0; m < 4; ++m)
        acc[m][n] = __builtin_amdgcn_mfma_f32_16x16x32_bf16(af[m], bf, acc[m][n], 0, 0, 0);
    }
  }

#pragma unroll
  for (int n = 0; n < 3; ++n) {
    int col = n0 + wn * 48 + n * 16 + (lane & 15);
    float bb = bout[(size_t)e * H_ + col];
#pragma unroll
    for (int m = 0; m < 4; ++m) {
#pragma unroll
      for (int q = 0; q < 4; ++q) {
        int r = wm * 64 + m * 16 + (lane >> 4) * 4 + q;
        if (row0 + r < n_e) {
          int g = rbase + row0 + r;
          int tok = tokl[g];
          float w = assw[g];
          atomicAdd(&out[(size_t)tok * H_ + col], w * (acc[m][n][q] + bb));
        }
      }
    }
  }
}

// ---------------- launch ----------------
extern "C" void kernel_launch(void* const* d_in, const int* in_sizes, int n_in,
                              void* d_out, int out_size, void* d_ws, size_t ws_size,
                              hipStream_t stream) {
  (void)in_sizes; (void)n_in; (void)ws_size;
  const float* x        = (const float*)d_in[0];
  const float* W_in     = (const float*)d_in[1];
  const float* b_in     = (const float*)d_in[2];
  const float* W_out    = (const float*)d_in[3];
  const float* b_out    = (const float*)d_in[4];
  const float* router_w = (const float*)d_in[5];
  const float* router_b = (const float*)d_in[6];
  float* out = (float*)d_out;
  char* ws = (char*)d_ws;

  int*   counts  = (int*)(ws + WS_COUNTS);
  int*   fill    = (int*)(ws + WS_FILL);
  int*   basep   = (int*)(ws + WS_BASE);
  int*   sched_e = (int*)(ws + WS_SCHED_E);
  int*   sched_r = (int*)(ws + WS_SCHED_R);
  int*   idx2    = (int*)(ws + WS_IDX2);
  float* wtop    = (float*)(ws + WS_W2);
  float* probs   = (float*)(ws + WS_PROBS);
  float* ent     = (float*)(ws + WS_ENT);
  int*   tokl    = (int*)(ws + WS_TOKL);
  float* assw    = (float*)(ws + WS_ASSW);
  unsigned short* actp = (unsigned short*)(ws + WS_ACT);

  hipMemsetAsync(d_ws, 0, 1024, stream);
  hipMemsetAsync(d_out, 0, (size_t)out_size * sizeof(float), stream);

  k_router<<<S_ / 4, 256, 0, stream>>>(x, router_w, router_b, counts, idx2, wtop, probs, ent);
  k_finalize<<<1, 256, 0, stream>>>(counts, probs, ent, idx2, wtop,
                                    out + (size_t)S_ * H_, basep, sched_e, sched_r);
  k_fill<<<S_ / 256, 256, 0, stream>>>(idx2, wtop, basep, fill, tokl, assw);
  k_gemm1<<<dim3(30, 48), 256, 0, stream>>>(x, W_in, b_in, sched_e, sched_r, basep,
                                            counts, tokl, actp);
  k_gemm2<<<dim3(30, 48), 256, 0, stream>>>(actp, W_out, b_out, sched_e, sched_r, basep,
                                            counts, tokl, assw, out);
}

// Round 2
// 863.797 us; speedup vs baseline: 1.1187x; 1.1187x over previous
//
#include <hip/hip_runtime.h>
#include <hip/hip_bf16.h>
#include <cstdint>
#include <cstddef>

#define H_ 2880
#define E_ 8
#define FF_ 2880
#define TWO_FF 5760
#define S_ 2048
#define NTOT 4096
#define CLIPV 7.0f
#define AUXC 0.01f
#define NKG 45            // 2880 / 64
#define GRID_G 1280
#define CPX 160           // GRID_G / 8

typedef __attribute__((ext_vector_type(8))) short bf16x8;
typedef __attribute__((ext_vector_type(4))) float f32x4;

// ---------------- workspace layout (bytes) ----------------
#define WS_COUNTS   0         // int[8]
#define WS_FILL     32        // int[8]
#define WS_BASE     64        // int[9]
#define WS_NS       104       // int
#define WS_SCHED_E  128       // int[1200]
#define WS_SCHED_C  4928      // int[1200]
#define WS_SCHED_R  9728      // int[1200]
#define WS_IDX2     14592     // int[2*S]
#define WS_W2       30976     // float[2*S]
#define WS_PROBS    47360     // float[8*S]
#define WS_ENT      112896    // float[S]
#define WS_TOKL     121088    // int[4096]
#define WS_ASSW     137472    // float[4096]
#define WS_AG       153856    // ushort[(4096+128)*2880] bf16 gathered x
#define WS_ACT      24484096  // ushort[(4096+128)*2880] bf16 act

typedef const __attribute__((address_space(1))) void global_cvoid;
typedef __attribute__((address_space(3))) void lds_void;

__device__ __forceinline__ void gload_lds16(const void* g, void* l) {
  __builtin_amdgcn_global_load_lds((global_cvoid*)g, (lds_void*)l, 16, 0, 0);
}

__device__ __forceinline__ unsigned int pack2bf(float a, float b) {
  __hip_bfloat162 h = __float22bfloat162_rn(make_float2(a, b));
  union { __hip_bfloat162 h; unsigned int u; } c; c.h = h; return c.u;
}

__device__ __forceinline__ unsigned short f2bf1(float f) {
  __hip_bfloat16 h = __float2bfloat16(f);
  union { __hip_bfloat16 h; unsigned short u; } c; c.h = h; return c.u;
}

// ---------------- router: logits, top2, probs, entropy ----------------
__global__ void k_router(const float* __restrict__ x, const float* __restrict__ rw,
                         const float* __restrict__ rb, int* __restrict__ counts,
                         int* __restrict__ idx2, float* __restrict__ wtop,
                         float* __restrict__ probs, float* __restrict__ ent) {
  int wave = threadIdx.x >> 6, lane = threadIdx.x & 63;
  int s = blockIdx.x * 4 + wave;
  if (s >= S_) return;
  const float* xr = x + (size_t)s * H_;
  float acc[E_];
#pragma unroll
  for (int e = 0; e < E_; ++e) acc[e] = 0.f;
  for (int k = lane; k < H_; k += 64) {
    float xv = xr[k];
#pragma unroll
    for (int e = 0; e < E_; ++e) acc[e] = fmaf(xv, rw[e * H_ + k], acc[e]);
  }
#pragma unroll
  for (int e = 0; e < E_; ++e) {
#pragma unroll
    for (int off = 32; off > 0; off >>= 1) acc[e] += __shfl_xor(acc[e], off, 64);
    acc[e] += rb[e];
  }
  if (lane == 0) {
    int i1 = 0; float v1 = acc[0];
#pragma unroll
    for (int e = 1; e < E_; ++e) if (acc[e] > v1) { v1 = acc[e]; i1 = e; }
    int i2 = -1; float v2 = -3.4e38f;
#pragma unroll
    for (int e = 0; e < E_; ++e) if (e != i1 && acc[e] > v2) { v2 = acc[e]; i2 = e; }
    float w1 = 1.f / (1.f + expf(v2 - v1));
    float w2v = 1.f - w1;
    float m = v1;
    float se = 0.f; float p[E_];
#pragma unroll
    for (int e = 0; e < E_; ++e) { p[e] = expf(acc[e] - m); se += p[e]; }
    float inv = 1.f / se; float ents = 0.f;
#pragma unroll
    for (int e = 0; e < E_; ++e) {
      p[e] *= inv;
      ents -= p[e] * logf(p[e] + 1e-10f);
      probs[(size_t)s * E_ + e] = p[e];
    }
    ent[s] = ents;
    idx2[2 * s] = i1; idx2[2 * s + 1] = i2;
    wtop[2 * s] = w1; wtop[2 * s + 1] = w2v;
    atomicAdd(&counts[i1], 1); atomicAdd(&counts[i2], 1);
  }
}

// ---------------- finalize: scalars + schedule ----------------
__global__ void k_finalize(const int* __restrict__ counts, const float* __restrict__ probs,
                           const float* __restrict__ ent, const int* __restrict__ idx2,
                           const float* __restrict__ wtop, float* __restrict__ outsc,
                           int* __restrict__ base, int* __restrict__ sched_e,
                           int* __restrict__ sched_c, int* __restrict__ sched_r,
                           int* __restrict__ nsp) {
  __shared__ float red[256];
  __shared__ float tot[17];
  int t = threadIdx.x;
  float imp[8], ld[8]; float es = 0.f;
#pragma unroll
  for (int e = 0; e < 8; ++e) { imp[e] = 0.f; ld[e] = 0.f; }
  for (int s = t; s < S_; s += 256) {
#pragma unroll
    for (int e = 0; e < 8; ++e) imp[e] += probs[(size_t)s * 8 + e];
    es += ent[s];
    int e0 = idx2[2 * s], e1 = idx2[2 * s + 1];
    float a = wtop[2 * s], b = wtop[2 * s + 1];
#pragma unroll
    for (int e = 0; e < 8; ++e)
      ld[e] += (e0 == e ? a : 0.f) + (e1 == e ? b : 0.f);
  }
#pragma unroll
  for (int q = 0; q < 17; ++q) {
    float v = (q < 8) ? imp[q] : ((q < 16) ? ld[q - 8] : es);
    red[t] = v; __syncthreads();
    for (int o = 128; o > 0; o >>= 1) { if (t < o) red[t] += red[t + o]; __syncthreads(); }
    if (t == 0) tot[q] = red[0];
    __syncthreads();
  }
  if (t == 0) {
    float aux = 0.f;
#pragma unroll
    for (int e = 0; e < 8; ++e) aux += (tot[e] / (float)S_) * (tot[8 + e] / (float)S_);
    aux *= AUXC * (float)E_;
    outsc[0] = aux;
#pragma unroll
    for (int e = 0; e < 8; ++e) outsc[1 + e] = tot[8 + e] / (float)S_;
    outsc[9] = tot[16] / (float)S_;
    int b0 = 0; base[0] = 0;
    for (int e = 0; e < 8; ++e) { b0 += counts[e]; base[e + 1] = b0; }
    int ns = 0;
    for (int e = 0; e < 8; ++e) {
      int c = counts[e];
      for (int col = 0; col < 30; ++col)
        for (int r = 0; r < c; r += 128) {
          sched_e[ns] = e; sched_c[ns] = col; sched_r[ns] = r; ++ns;
        }
    }
    nsp[0] = ns;
  }
}

// ---------------- fill per-expert token lists ----------------
__global__ void k_fill(const int* __restrict__ idx2, const float* __restrict__ wtop,
                       const int* __restrict__ base, int* __restrict__ fill,
                       int* __restrict__ tokl, float* __restrict__ assw) {
  int s = blockIdx.x * 256 + threadIdx.x;
  if (s >= S_) return;
#pragma unroll
  for (int k = 0; k < 2; ++k) {
    int e = idx2[2 * s + k];
    int p = base[e] + atomicAdd(&fill[e], 1);
    tokl[p] = s;
    assw[p] = wtop[2 * s + k];
  }
}

// ---------------- gather x rows -> bf16 ----------------
__global__ void k_gather(const float* __restrict__ x, const int* __restrict__ tokl,
                         unsigned short* __restrict__ Ag) {
  int g = blockIdx.x;
  int tok = tokl[g];
  const float2* src = (const float2*)(x + (size_t)tok * H_);
  unsigned int* dst = (unsigned int*)(Ag + (size_t)g * H_);
  for (int i = threadIdx.x; i < H_ / 2; i += 256)
    dst[i] = pack2bf(src[i].x, src[i].y);
}

// ---------------- GEMM1: Ag -> act (up/gate fused, bias+clip+silu) ----------------
__global__ __launch_bounds__(256, 2) void k_gemm1(
    const unsigned short* __restrict__ Ag, const float* __restrict__ Win,
    const float* __restrict__ bin, const int* __restrict__ sched_e,
    const int* __restrict__ sched_c, const int* __restrict__ sched_r,
    const int* __restrict__ base, const int* __restrict__ counts,
    const int* __restrict__ nsp, unsigned short* __restrict__ act) {
  int lid = (blockIdx.x & 7) * CPX + (blockIdx.x >> 3);
  if (lid >= nsp[0]) return;
  int e = sched_e[lid], col = sched_c[lid], row0 = sched_r[lid];
  int n_e = counts[e], rbase = base[e];
  int n0 = col * 96;
  const float* We = Win + (size_t)e * H_ * TWO_FF;
  int tid = threadIdx.x, lane = tid & 63, wv = tid >> 6;
  int wm = wv >> 1, wn = wv & 1;

  __shared__ __align__(16) unsigned short Al[8][128][8];
  __shared__ __align__(16) unsigned short Bc[2][8][96][8];

  // A chunks via global_load_lds (bf16, linear dest)
  const unsigned short* asrc[4];
  char* adst[4];
#pragma unroll
  for (int i = 0; i < 4; ++i) {
    int u = wv * 4 + i, k8 = u >> 1, rh = u & 1;
    asrc[i] = Ag + (size_t)(rbase + row0 + rh * 64 + lane) * H_ + k8 * 8;
    adst[i] = (char*)&Al[k8][rh * 64][0];
  }
  // B staging maps (12 x 4 fp32 per thread per K-step)
  unsigned int b_off[12]; int b_loff[12];
#pragma unroll
  for (int li = 0; li < 12; ++li) {
    int c = tid + 256 * li;
    int kq = c / 192, j = c - kq * 192;
    int tile = (j >= 96) ? 1 : 0, jj = j - tile * 96;
    b_off[li] = (unsigned)(kq * 4) * TWO_FF + (unsigned)(n0 + jj + tile * FF_);
    b_loff[li] = tile * 12288 + (kq >> 1) * 1536 + jj * 16 + (kq & 1) * 8;
  }

  f32x4 aU[4][3], aG[4][3];
#pragma unroll
  for (int m = 0; m < 4; ++m)
#pragma unroll
    for (int n = 0; n < 3; ++n) { aU[m][n] = (f32x4)0.f; aG[m][n] = (f32x4)0.f; }

  float bv[12][4];
#pragma unroll
  for (int li = 0; li < 12; ++li) {
    const float* p = We + b_off[li];
    bv[li][0] = p[0]; bv[li][1] = p[TWO_FF]; bv[li][2] = p[2 * TWO_FF]; bv[li][3] = p[3 * TWO_FF];
  }
  char* BcB = (char*)&Bc[0][0][0][0];

  for (int kt = 0; kt < NKG; ++kt) {
    __syncthreads();
#pragma unroll
    for (int i = 0; i < 4; ++i)
      gload_lds16(asrc[i] + (size_t)kt * 64, adst[i]);
#pragma unroll
    for (int li = 0; li < 12; ++li) {
      uint2 v;
      v.x = pack2bf(bv[li][0], bv[li][1]);
      v.y = pack2bf(bv[li][2], bv[li][3]);
      *(uint2*)(BcB + b_loff[li]) = v;
    }
    if (kt + 1 < NKG) {
      size_t koff = (size_t)(kt + 1) * 64 * TWO_FF;
#pragma unroll
      for (int li = 0; li < 12; ++li) {
        const float* p = We + b_off[li] + koff;
        bv[li][0] = p[0]; bv[li][1] = p[TWO_FF]; bv[li][2] = p[2 * TWO_FF]; bv[li][3] = p[3 * TWO_FF];
      }
    }
    __syncthreads();
#pragma unroll
    for (int kk = 0; kk < 2; ++kk) {
      bf16x8 af[4];
#pragma unroll
      for (int m = 0; m < 4; ++m)
        af[m] = *(const bf16x8*)&Al[kk * 4 + (lane >> 4)][wm * 64 + m * 16 + (lane & 15)][0];
#pragma unroll
      for (int n = 0; n < 3; ++n) {
        bf16x8 bu = *(const bf16x8*)&Bc[0][kk * 4 + (lane >> 4)][wn * 48 + n * 16 + (lane & 15)][0];
        bf16x8 bg = *(const bf16x8*)&Bc[1][kk * 4 + (lane >> 4)][wn * 48 + n * 16 + (lane & 15)][0];
#pragma unroll
        for (int m = 0; m < 4; ++m) {
          aU[m][n] = __builtin_amdgcn_mfma_f32_16x16x32_bf16(af[m], bu, aU[m][n], 0, 0, 0);
          aG[m][n] = __builtin_amdgcn_mfma_f32_16x16x32_bf16(af[m], bg, aG[m][n], 0, 0, 0);
        }
      }
    }
  }

  float bias_u[3], bias_g[3];
#pragma unroll
  for (int n = 0; n < 3; ++n) {
    int cidx = n0 + wn * 48 + n * 16 + (lane & 15);
    bias_u[n] = bin[(size_t)e * TWO_FF + cidx];
    bias_g[n] = bin[(size_t)e * TWO_FF + FF_ + cidx];
  }
#pragma unroll
  for (int m = 0; m < 4; ++m) {
#pragma unroll
    for (int q = 0; q < 4; ++q) {
      int r = wm * 64 + m * 16 + (lane >> 4) * 4 + q;
      if (row0 + r < n_e) {
        size_t rowp = (size_t)(rbase + row0 + r) * FF_;
#pragma unroll
        for (int n = 0; n < 3; ++n) {
          int cidx = n0 + wn * 48 + n * 16 + (lane & 15);
          float u = aU[m][n][q] + bias_u[n];
          float g = aG[m][n][q] + bias_g[n];
          u = fminf(fmaxf(u, -CLIPV), CLIPV);
          g = fminf(fmaxf(g, -CLIPV), CLIPV);
          float sig = 1.f / (1.f + expf(-g));
          act[rowp + cidx] = f2bf1(g * sig * u);
        }
      }
    }
  }
}

// ---------------- GEMM2: act -> out (scatter-add weighted) ----------------
__global__ __launch_bounds__(256, 2) void k_gemm2(
    const unsigned short* __restrict__ act, const float* __restrict__ Wout,
    const float* __restrict__ bout, const int* __restrict__ sched_e,
    const int* __restrict__ sched_c, const int* __restrict__ sched_r,
    const int* __restrict__ base, const int* __restrict__ counts,
    const int* __restrict__ nsp, const int* __restrict__ tokl,
    const float* __restrict__ assw, float* __restrict__ out) {
  int lid = (blockIdx.x & 7) * CPX + (blockIdx.x >> 3);
  if (lid >= nsp[0]) return;
  int e = sched_e[lid], col = sched_c[lid], row0 = sched_r[lid];
  int n_e = counts[e], rbase = base[e];
  int n0 = col * 96;
  const float* We = Wout + (size_t)e * FF_ * H_;
  int tid = threadIdx.x, lane = tid & 63, wv = tid >> 6;
  int wm = wv >> 1, wn = wv & 1;

  __shared__ __align__(16) unsigned short Al[8][128][8];
  __shared__ __align__(16) unsigned short Bl[8][96][8];

  const unsigned short* asrc[4];
  char* adst[4];
#pragma unroll
  for (int i = 0; i < 4; ++i) {
    int u = wv * 4 + i, k8 = u >> 1, rh = u & 1;
    asrc[i] = act + (size_t)(rbase + row0 + rh * 64 + lane) * FF_ + k8 * 8;
    adst[i] = (char*)&Al[k8][rh * 64][0];
  }
  unsigned int b_off[6]; int b_loff[6];
#pragma unroll
  for (int li = 0; li < 6; ++li) {
    int c = tid + 256 * li;
    int kq = c / 96, j = c - kq * 96;
    b_off[li] = (unsigned)(kq * 4) * H_ + (unsigned)(n0 + j);
    b_loff[li] = (kq >> 1) * 1536 + j * 16 + (kq & 1) * 8;
  }

  f32x4 acc[4][3];
#pragma unroll
  for (int m = 0; m < 4; ++m)
#pragma unroll
    for (int n = 0; n < 3; ++n) acc[m][n] = (f32x4)0.f;

  float bv[6][4];
#pragma unroll
  for (int li = 0; li < 6; ++li) {
    const float* p = We + b_off[li];
    bv[li][0] = p[0]; bv[li][1] = p[H_]; bv[li][2] = p[2 * H_]; bv[li][3] = p[3 * H_];
  }
  char* BlB = (char*)&Bl[0][0][0];

  for (int kt = 0; kt < NKG; ++kt) {
    __syncthreads();
#pragma unroll
    for (int i = 0; i < 4; ++i)
      gload_lds16(asrc[i] + (size_t)kt * 64, adst[i]);
#pragma unroll
    for (int li = 0; li < 6; ++li) {
      uint2 v;
      v.x = pack2bf(bv[li][0], bv[li][1]);
      v.y = pack2bf(bv[li][2], bv[li][3]);
      *(uint2*)(BlB + b_loff[li]) = v;
    }
    if (kt + 1 < NKG) {
      size_t koff = (size_t)(kt + 1) * 64 * H_;
#pragma unroll
      for (int li = 0; li < 6; ++li) {
        const float* p = We + b_off[li] + koff;
        bv[li][0] = p[0]; bv[li][1] = p[H_]; bv[li][2] = p[2 * H_]; bv[li][3] = p[3 * H_];
      }
    }
    __syncthreads();
#pragma unroll
    for (int kk = 0; kk < 2; ++kk) {
      bf16x8 af[4];
#pragma unroll
      for (int m = 0; m < 4; ++m)
        af[m] = *(const bf16x8*)&Al[kk * 4 + (lane >> 4)][wm * 64 + m * 16 + (lane & 15)][0];
#pragma unroll
      for (int n = 0; n < 3; ++n) {
        bf16x8 bf = *(const bf16x8*)&Bl[kk * 4 + (lane >> 4)][wn * 48 + n * 16 + (lane & 15)][0];
#pragma unroll
        for (int m = 0; m < 4; ++m)
          acc[m][n] = __builtin_amdgcn_mfma_f32_16x16x32_bf16(af[m], bf, acc[m][n], 0, 0, 0);
      }
    }
  }

  float bb[3];
#pragma unroll
  for (int n = 0; n < 3; ++n)
    bb[n] = bout[(size_t)e * H_ + n0 + wn * 48 + n * 16 + (lane & 15)];
#pragma unroll
  for (int m = 0; m < 4; ++m) {
#pragma unroll
    for (int q = 0; q < 4; ++q) {
      int r = wm * 64 + m * 16 + (lane >> 4) * 4 + q;
      if (row0 + r < n_e) {
        int g = rbase + row0 + r;
        int tok = tokl[g];
        float w = assw[g];
        float* orow = out + (size_t)tok * H_;
#pragma unroll
        for (int n = 0; n < 3; ++n) {
          int cidx = n0 + wn * 48 + n * 16 + (lane & 15);
          atomicAdd(&orow[cidx], w * (acc[m][n][q] + bb[n]));
        }
      }
    }
  }
}

// ---------------- launch ----------------
extern "C" void kernel_launch(void* const* d_in, const int* in_sizes, int n_in,
                              void* d_out, int out_size, void* d_ws, size_t ws_size,
                              hipStream_t stream) {
  (void)in_sizes; (void)n_in; (void)ws_size;
  const float* x        = (const float*)d_in[0];
  const float* W_in     = (const float*)d_in[1];
  const float* b_in     = (const float*)d_in[2];
  const float* W_out    = (const float*)d_in[3];
  const float* b_out    = (const float*)d_in[4];
  const float* router_w = (const float*)d_in[5];
  const float* router_b = (const float*)d_in[6];
  float* out = (float*)d_out;
  char* ws = (char*)d_ws;

  int*   counts  = (int*)(ws + WS_COUNTS);
  int*   fill    = (int*)(ws + WS_FILL);
  int*   basep   = (int*)(ws + WS_BASE);
  int*   nsp     = (int*)(ws + WS_NS);
  int*   sched_e = (int*)(ws + WS_SCHED_E);
  int*   sched_c = (int*)(ws + WS_SCHED_C);
  int*   sched_r = (int*)(ws + WS_SCHED_R);
  int*   idx2    = (int*)(ws + WS_IDX2);
  float* wtop    = (float*)(ws + WS_W2);
  float* probs   = (float*)(ws + WS_PROBS);
  float* ent     = (float*)(ws + WS_ENT);
  int*   tokl    = (int*)(ws + WS_TOKL);
  float* assw    = (float*)(ws + WS_ASSW);
  unsigned short* Ag   = (unsigned short*)(ws + WS_AG);
  unsigned short* actp = (unsigned short*)(ws + WS_ACT);

  hipMemsetAsync(d_ws, 0, 1024, stream);
  hipMemsetAsync(d_out, 0, (size_t)out_size * sizeof(float), stream);

  k_router<<<S_ / 4, 256, 0, stream>>>(x, router_w, router_b, counts, idx2, wtop, probs, ent);
  k_finalize<<<1, 256, 0, stream>>>(counts, probs, ent, idx2, wtop,
                                    out + (size_t)S_ * H_, basep, sched_e, sched_c, sched_r, nsp);
  k_fill<<<S_ / 256, 256, 0, stream>>>(idx2, wtop, basep, fill, tokl, assw);
  k_gather<<<NTOT, 256, 0, stream>>>(x, tokl, Ag);
  k_gemm1<<<GRID_G, 256, 0, stream>>>(Ag, W_in, b_in, sched_e, sched_c, sched_r,
                                      basep, counts, nsp, actp);
  k_gemm2<<<GRID_G, 256, 0, stream>>>(actp, W_out, b_out, sched_e, sched_c, sched_r,
                                      basep, counts, nsp, tokl, assw, out);
}